// Round 1
// baseline (481.541 us; speedup 1.0000x reference)
//
#include <hip/hip_runtime.h>

// BilinearSampler: U[B,H,W,C] f32, grid[B,H,W,2] f32 -> out[B,H,W,C] f32
// B=16, H=256, W=256, C=64.
// Layout: 16 threads per output pixel, each thread owns 4 channels (float4).
// All corner reads are global_load_dwordx4, coalesced across the 16-thread
// pixel group (4 x 256B segments per wave).

#define BB 16
#define HH 256
#define WW 256
#define CC 64

__global__ __launch_bounds__(256) void
bilinear_kernel(const float* __restrict__ U,
                const float* __restrict__ grid,
                float* __restrict__ out) {
    const int tid   = blockIdx.x * 256 + threadIdx.x;
    const int pixel = tid >> 4;                // global pixel index in [0, B*H*W)
    const int c0    = (tid & 15) << 2;         // channel offset (0..60 step 4)

    // grid coords (all 16 threads of a pixel read the same 8 bytes -> L1 broadcast)
    const float2 g = ((const float2*)grid)[pixel];
    const float x = 0.5f * ((g.x + 1.0f) * (float)(WW - 1));
    const float y = 0.5f * ((g.y + 1.0f) * (float)(HH - 1));

    const float xf = floorf(x);
    const float yf = floorf(y);
    int x0 = (int)xf;
    int y0 = (int)yf;
    int x1 = x0 + 1;
    int y1 = y0 + 1;

    const int x0c = min(max(x0, 0), WW - 1);
    const int x1c = min(max(x1, 0), WW - 1);
    const int y0c = min(max(y0, 0), HH - 1);
    const int y1c = min(max(y1, 0), HH - 1);

    const float x0f = (float)x0c, x1f = (float)x1c;
    const float y0f = (float)y0c, y1f = (float)y1c;

    const float wa = (x1f - x) * (y1f - y);
    const float wb = (x1f - x) * (y - y0f);
    const float wc = (x - x0f) * (y1f - y);
    const float wd = (x - x0f) * (y - y0f);

    const int b = pixel >> 16;                 // pixel / (H*W), H*W = 65536
    const size_t base = (size_t)b * (HH * WW * CC) + c0;

    const size_t offA = base + ((size_t)(y0c * WW + x0c)) * CC;
    const size_t offB = base + ((size_t)(y1c * WW + x0c)) * CC;
    const size_t offC = base + ((size_t)(y0c * WW + x1c)) * CC;
    const size_t offD = base + ((size_t)(y1c * WW + x1c)) * CC;

    const float4 Ia = *(const float4*)(U + offA);
    const float4 Ib = *(const float4*)(U + offB);
    const float4 Ic = *(const float4*)(U + offC);
    const float4 Id = *(const float4*)(U + offD);

    float4 r;
    r.x = wa * Ia.x + wb * Ib.x + wc * Ic.x + wd * Id.x;
    r.y = wa * Ia.y + wb * Ib.y + wc * Ic.y + wd * Id.y;
    r.z = wa * Ia.z + wb * Ib.z + wc * Ic.z + wd * Id.z;
    r.w = wa * Ia.w + wb * Ib.w + wc * Ic.w + wd * Id.w;

    *(float4*)(out + (size_t)pixel * CC + c0) = r;
}

extern "C" void kernel_launch(void* const* d_in, const int* in_sizes, int n_in,
                              void* d_out, int out_size, void* d_ws, size_t ws_size,
                              hipStream_t stream) {
    const float* U    = (const float*)d_in[0];
    const float* grid = (const float*)d_in[1];
    float* out        = (float*)d_out;

    const int n_pixels = BB * HH * WW;              // 1,048,576
    const int n_threads = n_pixels * 16;            // 16,777,216
    const int n_blocks = n_threads / 256;           // 65,536

    bilinear_kernel<<<n_blocks, 256, 0, stream>>>(U, grid, out);
}

// Round 2
// 478.907 us; speedup vs baseline: 1.0055x; 1.0055x over previous
//
#include <hip/hip_runtime.h>

// BilinearSampler: U[B,H,W,C] f32, grid[B,H,W,2] f32 -> out[B,H,W,C] f32
// B=16, H=256, W=256, C=64.
// Layout: 16 threads per output pixel, each thread owns 4 channels (float4).
// v2: non-temporal stores for out + non-temporal loads for grid, so the
// 256 MB write stream / 8 MB read-once grid don't evict cached U lines
// (U has 4.2x logical reuse; keeping it resident in L2/L3 is the whole game).

#define BB 16
#define HH 256
#define WW 256
#define CC 64

typedef float vfloat4 __attribute__((ext_vector_type(4)));
typedef float vfloat2 __attribute__((ext_vector_type(2)));

__global__ __launch_bounds__(256) void
bilinear_kernel(const float* __restrict__ U,
                const float* __restrict__ grid,
                float* __restrict__ out) {
    const int tid   = blockIdx.x * 256 + threadIdx.x;
    const int pixel = tid >> 4;                // global pixel index in [0, B*H*W)
    const int c0    = (tid & 15) << 2;         // channel offset (0..60 step 4)

    // grid coords: read-once stream -> non-temporal (don't pollute caches)
    const vfloat2 g = __builtin_nontemporal_load((const vfloat2*)grid + pixel);
    const float x = 0.5f * ((g.x + 1.0f) * (float)(WW - 1));
    const float y = 0.5f * ((g.y + 1.0f) * (float)(HH - 1));

    const float xf = floorf(x);
    const float yf = floorf(y);
    int x0 = (int)xf;
    int y0 = (int)yf;
    int x1 = x0 + 1;
    int y1 = y0 + 1;

    const int x0c = min(max(x0, 0), WW - 1);
    const int x1c = min(max(x1, 0), WW - 1);
    const int y0c = min(max(y0, 0), HH - 1);
    const int y1c = min(max(y1, 0), HH - 1);

    const float x0f = (float)x0c, x1f = (float)x1c;
    const float y0f = (float)y0c, y1f = (float)y1c;

    const float wa = (x1f - x) * (y1f - y);
    const float wb = (x1f - x) * (y - y0f);
    const float wc = (x - x0f) * (y1f - y);
    const float wd = (x - x0f) * (y - y0f);

    const int b = pixel >> 16;                 // pixel / (H*W), H*W = 65536
    const size_t base = (size_t)b * (HH * WW * CC) + c0;

    const size_t offA = base + ((size_t)(y0c * WW + x0c)) * CC;
    const size_t offB = base + ((size_t)(y1c * WW + x0c)) * CC;
    const size_t offC = base + ((size_t)(y0c * WW + x1c)) * CC;
    const size_t offD = base + ((size_t)(y1c * WW + x1c)) * CC;

    // U reads: cached (4.2x reuse within the 16 MB batch slice)
    const float4 Ia = *(const float4*)(U + offA);
    const float4 Ib = *(const float4*)(U + offB);
    const float4 Ic = *(const float4*)(U + offC);
    const float4 Id = *(const float4*)(U + offD);

    vfloat4 r;
    r.x = wa * Ia.x + wb * Ib.x + wc * Ic.x + wd * Id.x;
    r.y = wa * Ia.y + wb * Ib.y + wc * Ic.y + wd * Id.y;
    r.z = wa * Ia.z + wb * Ib.z + wc * Ic.z + wd * Id.z;
    r.w = wa * Ia.w + wb * Ib.w + wc * Ic.w + wd * Id.w;

    // output: pure write stream -> non-temporal store
    __builtin_nontemporal_store(r, (vfloat4*)(out + (size_t)pixel * CC + c0));
}

extern "C" void kernel_launch(void* const* d_in, const int* in_sizes, int n_in,
                              void* d_out, int out_size, void* d_ws, size_t ws_size,
                              hipStream_t stream) {
    const float* U    = (const float*)d_in[0];
    const float* grid = (const float*)d_in[1];
    float* out        = (float*)d_out;

    const int n_pixels = BB * HH * WW;              // 1,048,576
    const int n_threads = n_pixels * 16;            // 16,777,216
    const int n_blocks = n_threads / 256;           // 65,536

    bilinear_kernel<<<n_blocks, 256, 0, stream>>>(U, grid, out);
}